// Round 8
// baseline (369.172 us; speedup 1.0000x reference)
//
#include <hip/hip_runtime.h>

// Problem constants (from reference): B=16, C=64, H=128, W=128, fp32.
// Outputs concatenated: [sobel_x_f1, sobel_y_f1, sobel_x_f2, sobel_y_f2].
#define BB 16
#define CC 64
#define HH 128
#define WW 128
#define TH 32                      // rows per block tile (halo over-fetch 34/32 = 1.0625x)
#define NTILES (HH / TH)           // 4 row-tiles per plane
#define PLANES (BB*CC)             // 1024
#define PLANE_SZ (HH*WW)           // 16384
#define NTOT ((size_t)PLANES*PLANE_SZ)  // 16,777,216 elements per output tensor
#define LDW 132                    // LDS row stride: %4==0 (aligned float4 reads),
                                   // %32==4 (rows rotate banks). Pixel x at col x+2.

// Native clang vector type: __builtin_nontemporal_store accepts this
// (HIP_vector_type float4 is a struct and is rejected).
typedef float f32x4 __attribute__((ext_vector_type(4)));

__global__ __launch_bounds__(256)
void sobel_fused_kernel(const float* __restrict__ f1,
                        const float* __restrict__ f2,
                        float* __restrict__ out) {
    // 34 * 132 * 4 B = 17.95 KB -> ~8 blocks/CU by LDS (not the limiter).
    __shared__ float tile[TH + 2][LDW];

    // ---- XCD-locality decode: same-plane tiles -> same XCD (xcd = L % 8
    // round-robin heuristic; perf-only, correctness never depends on it).
    // Encode was L = ((pg>>3)*4 + t)*8 + (pg&7), pg = which*1024 + plane.
    // Decode verified bijective: L&7 -> pg low bits; s=L>>3; t=s&3; pg=(s>>2)<<3|(L&7).
    const int L  = blockIdx.x;        // 0..8191
    const int s  = L >> 3;            // 0..1023
    const int t  = s & 3;             // row-tile 0..3
    const int pg = ((s >> 2) << 3) + (L & 7);  // 0..2047
    const int which = pg >> 10;       // 0: f1, 1: f2
    const int plane = pg & 1023;      // b*C + c

    const float* in = (which == 0 ? f1 : f2) + (size_t)plane * PLANE_SZ;
    float* out_sx = out + (size_t)(2 * which) * NTOT + (size_t)plane * PLANE_SZ;
    float* out_sy = out_sx + NTOT;

    const int y0  = t * TH;
    const int tid = threadIdx.x + threadIdx.y * 32;  // 0..255

    // ---- Stage (TH+2) rows x 128 floats into LDS, coalesced float4 loads ----
    // 34 rows * 32 float4-chunks = 1088 chunks; 256 threads -> <=5 per thread.
    for (int idx = tid; idx < (TH + 2) * 32; idx += 256) {
        const int r  = idx >> 5;      // 0..33 (row y0 + r - 1)
        const int c4 = idx & 31;      // 0..31 (float4 chunk)
        const int gy = y0 + r - 1;
        f32x4 v = {0.f, 0.f, 0.f, 0.f};
        if (gy >= 0 && gy < HH) {
            v = *reinterpret_cast<const f32x4*>(in + (size_t)gy * WW + c4 * 4);
        }
        float* dst = &tile[r][2 + c4 * 4];   // pixel x -> col x+2 (8B-aligned)
        dst[0] = v.x; dst[1] = v.y; dst[2] = v.z; dst[3] = v.w;
    }
    // Zero the left/right halo columns (cols 0,1 and 130,131).
    if (tid < TH + 2) {
        tile[tid][0]   = 0.f;
        tile[tid][1]   = 0.f;
        tile[tid][130] = 0.f;
        tile[tid][131] = 0.f;
    }
    __syncthreads();

    // ---- Compute: each thread does 4 rows, one float4 of gx/gy per row.
    // Pixels xb-1..xb+4 live in cols xb+1..xb+6 -> two ALIGNED float4 reads
    // per row (cols xb and xb+4; row stride 528 B is 16B-multiple):
    // 6x ds_read_b128 per row-iter instead of 18 conflicted ds_read_b32.
    const int tx = threadIdx.x;   // 0..31 -> pixel columns 4*tx..4*tx+3
    const int xb = tx * 4;

    #pragma unroll
    for (int rr = 0; rr < 4; ++rr) {
        const int ty = threadIdx.y + rr * 8;   // 0..31 -> output row y0+ty

        const f32x4 tA = *reinterpret_cast<const f32x4*>(&tile[ty][xb]);
        const f32x4 tB = *reinterpret_cast<const f32x4*>(&tile[ty][xb + 4]);
        const f32x4 mA = *reinterpret_cast<const f32x4*>(&tile[ty + 1][xb]);
        const f32x4 mB = *reinterpret_cast<const f32x4*>(&tile[ty + 1][xb + 4]);
        const f32x4 bA = *reinterpret_cast<const f32x4*>(&tile[ty + 2][xb]);
        const f32x4 bB = *reinterpret_cast<const f32x4*>(&tile[ty + 2][xb + 4]);

        // v[k] = pixel (xb-1+k); pixel p is at col p+2, so v[0..5] = cols
        // xb+1..xb+6 = A.y,A.z,A.w,B.x,B.y,B.z
        const float t0 = tA.y, t1 = tA.z, t2 = tA.w, t3 = tB.x, t4 = tB.y, t5 = tB.z;
        const float m0 = mA.y, m1 = mA.z, m2 = mA.w, m3 = mB.x, m4 = mB.y, m5 = mB.z;
        const float b0 = bA.y, b1 = bA.z, b2 = bA.w, b3 = bB.x, b4 = bB.y, b5 = bB.z;

        // SOBEL_X = [[1,0,-1],[2,0,-2],[1,0,-1]] (cross-correlation, no flip)
        f32x4 gx;
        gx.x = (t0 - t2) + 2.f * (m0 - m2) + (b0 - b2);
        gx.y = (t1 - t3) + 2.f * (m1 - m3) + (b1 - b3);
        gx.z = (t2 - t4) + 2.f * (m2 - m4) + (b2 - b4);
        gx.w = (t3 - t5) + 2.f * (m3 - m5) + (b3 - b5);

        // SOBEL_Y = [[1,2,1],[0,0,0],[-1,-2,-1]]
        f32x4 gy;
        gy.x = (t0 + 2.f * t1 + t2) - (b0 + 2.f * b1 + b2);
        gy.y = (t1 + 2.f * t2 + t3) - (b1 + 2.f * b2 + b3);
        gy.z = (t2 + 2.f * t3 + t4) - (b2 + 2.f * b3 + b4);
        gy.w = (t3 + 2.f * t4 + t5) - (b3 + 2.f * b4 + b5);

        // Nontemporal stores: outputs are write-once, never re-read in this
        // dispatch. `nt` keeps them from write-allocating in L2/L3 so input
        // rows (halo reuse) stay cache-resident.
        const int orow = y0 + ty;
        __builtin_nontemporal_store(gx, reinterpret_cast<f32x4*>(out_sx + (size_t)orow * WW + xb));
        __builtin_nontemporal_store(gy, reinterpret_cast<f32x4*>(out_sy + (size_t)orow * WW + xb));
    }
}

extern "C" void kernel_launch(void* const* d_in, const int* in_sizes, int n_in,
                              void* d_out, int out_size, void* d_ws, size_t ws_size,
                              hipStream_t stream) {
    const float* f1 = (const float*)d_in[0];
    const float* f2 = (const float*)d_in[1];
    float* out = (float*)d_out;

    dim3 grid(NTILES * PLANES * 2);  // 8192 blocks, 1D for the XCD swizzle
    dim3 block(32, 8);               // 256 threads
    sobel_fused_kernel<<<grid, block, 0, stream>>>(f1, f2, out);
}

// Round 10
// 366.190 us; speedup vs baseline: 1.0081x; 1.0081x over previous
//
#include <hip/hip_runtime.h>

// Sobel (x,y) on two inputs, fused. B=16,C=64,H=128,W=128 fp32.
// Outputs concatenated: [sobel_x_f1, sobel_y_f1, sobel_x_f2, sobel_y_f2].
//
// Register sliding-window stencil: no LDS, no barriers. Each thread owns a
// 4-px column strip; per input row it does ONE aligned f32x4 global load,
// gets the two neighbor pixels via __shfl from adjacent lanes, keeps a
// 3-row window in registers, and rotates. One block per (plane, input):
// band halo rows re-read by the adjacent band hit L1 (same CU), so HBM
// fetch ~= the exact 134 MB ideal.
#define HH 128
#define WW 128
#define PLANES 1024                       // B*C
#define PLANE_SZ (HH*WW)                  // 16384
#define NTOT ((size_t)PLANES*PLANE_SZ)    // elements per output tensor
#define BAND 16                           // rows per threadIdx.y band (8 bands)

typedef float f32x4 __attribute__((ext_vector_type(4)));

struct Win { float w0, w1, w2, w3, w4, w5; };  // pixels col-1 .. col+4

__device__ __forceinline__ Win load_win(const float* __restrict__ in,
                                        int y, int col, int tx) {
    f32x4 v = {0.f, 0.f, 0.f, 0.f};
    if (y >= 0 && y < HH)
        v = *reinterpret_cast<const f32x4*>(in + y * WW + col);
    // Neighbor exchange within the row (32 lanes per row; lanes tx and tx+-1).
    // Lane pairs (31,32) straddle two bands, but those reads are exactly the
    // x=-1 / x=128 zero-padding cases, overridden by the tx masks below.
    const float lw = __shfl_up(v.w, 1);
    const float rx = __shfl_down(v.x, 1);
    Win w;
    w.w0 = (tx == 0)  ? 0.f : lw;
    w.w1 = v.x; w.w2 = v.y; w.w3 = v.z; w.w4 = v.w;
    w.w5 = (tx == 31) ? 0.f : rx;
    return w;
}

__global__ __launch_bounds__(256, 4)
void sobel_fused_kernel(const float* __restrict__ f1,
                        const float* __restrict__ f2,
                        float* __restrict__ out) {
    const int blk   = blockIdx.x;     // 0..2047
    const int which = blk >> 10;      // 0: f1, 1: f2
    const int plane = blk & 1023;     // b*C + c

    const float* in = (which ? f2 : f1) + (size_t)plane * PLANE_SZ;
    float* out_sx = out + (size_t)(2 * which) * NTOT + (size_t)plane * PLANE_SZ;
    float* out_sy = out_sx + NTOT;

    const int tx  = threadIdx.x;          // 0..31 -> cols 4tx..4tx+3
    const int col = tx * 4;
    const int y0  = (int)threadIdx.y * BAND;  // 0..112 step 16

    // Prime the 3-row window: rows y0-1 and y0.
    Win rt = load_win(in, y0 - 1, col, tx);
    Win rm = load_win(in, y0,     col, tx);

    #pragma unroll
    for (int i = 0; i < BAND; ++i) {
        const int y = y0 + i;
        const Win rb = load_win(in, y + 1, col, tx);

        // SOBEL_X = [[1,0,-1],[2,0,-2],[1,0,-1]]  (cross-correlation, no flip)
        f32x4 gx;
        gx.x = (rt.w0 - rt.w2) + 2.f * (rm.w0 - rm.w2) + (rb.w0 - rb.w2);
        gx.y = (rt.w1 - rt.w3) + 2.f * (rm.w1 - rm.w3) + (rb.w1 - rb.w3);
        gx.z = (rt.w2 - rt.w4) + 2.f * (rm.w2 - rm.w4) + (rb.w2 - rb.w4);
        gx.w = (rt.w3 - rt.w5) + 2.f * (rm.w3 - rm.w5) + (rb.w3 - rb.w5);

        // SOBEL_Y = [[1,2,1],[0,0,0],[-1,-2,-1]]
        f32x4 gy;
        gy.x = (rt.w0 + 2.f * rt.w1 + rt.w2) - (rb.w0 + 2.f * rb.w1 + rb.w2);
        gy.y = (rt.w1 + 2.f * rt.w2 + rt.w3) - (rb.w1 + 2.f * rb.w2 + rb.w3);
        gy.z = (rt.w2 + 2.f * rt.w3 + rt.w4) - (rb.w2 + 2.f * rb.w3 + rb.w4);
        gy.w = (rt.w3 + 2.f * rt.w4 + rt.w5) - (rb.w3 + 2.f * rb.w4 + rb.w5);

        // Outputs are write-once, never re-read: nt stores keep them from
        // write-allocating in L2/L3 so input rows stay cache-resident.
        __builtin_nontemporal_store(gx, reinterpret_cast<f32x4*>(out_sx + (size_t)y * WW + col));
        __builtin_nontemporal_store(gy, reinterpret_cast<f32x4*>(out_sy + (size_t)y * WW + col));

        rt = rm; rm = rb;   // slide the window down
    }
}

extern "C" void kernel_launch(void* const* d_in, const int* in_sizes, int n_in,
                              void* d_out, int out_size, void* d_ws, size_t ws_size,
                              hipStream_t stream) {
    const float* f1 = (const float*)d_in[0];
    const float* f2 = (const float*)d_in[1];
    float* out = (float*)d_out;

    dim3 grid(PLANES * 2);   // one block per (plane, input) = 2048 blocks
    dim3 block(32, 8);       // 256 threads: 32 col-strips x 8 row-bands
    sobel_fused_kernel<<<grid, block, 0, stream>>>(f1, f2, out);
}

// Round 12
// 356.995 us; speedup vs baseline: 1.0341x; 1.0258x over previous
//
#include <hip/hip_runtime.h>

// Sobel (x,y) on two inputs, fused. B=16,C=64,H=128,W=128 fp32.
// Outputs concatenated: [sobel_x_f1, sobel_y_f1, sobel_x_f2, sobel_y_f2].
//
// Register stencil with BATCHED loads: per 8-row chunk each thread issues
// all 10 row-loads back-to-back (deep MLP, coarse HBM read burst), then
// computes, then writes 16 nt stores (coarse write burst). This replaces the
// previous 1-load-2-store fine-grained interleave that forces HBM
// read/write turnaround every ~1KB. No LDS, no barriers.
#define HH 128
#define WW 128
#define PLANES 1024                       // B*C
#define PLANE_SZ (HH*WW)                  // 16384
#define NTOT ((size_t)PLANES*PLANE_SZ)    // elements per output tensor
#define BAND 16                           // rows per threadIdx.y band (8 bands)
#define CHUNK 8                           // rows computed per load batch

typedef float f32x4 __attribute__((ext_vector_type(4)));

__global__ __launch_bounds__(256, 4)
void sobel_fused_kernel(const float* __restrict__ f1,
                        const float* __restrict__ f2,
                        float* __restrict__ out) {
    const int blk   = blockIdx.x;     // 0..2047
    const int which = blk >> 10;      // 0: f1, 1: f2
    const int plane = blk & 1023;     // b*C + c

    const float* in = (which ? f2 : f1) + (size_t)plane * PLANE_SZ;
    float* out_sx = out + (size_t)(2 * which) * NTOT + (size_t)plane * PLANE_SZ;
    float* out_sy = out_sx + NTOT;

    const int tx  = threadIdx.x;              // 0..31 -> cols 4tx..4tx+3
    const int col = tx * 4;
    const int y0  = (int)threadIdx.y * BAND;  // 0..112 step 16

    #pragma unroll
    for (int c = 0; c < BAND / CHUNK; ++c) {
        const int base = y0 + c * CHUNK;      // first output row of this chunk

        // ---- Load batch: rows base-1 .. base+CHUNK, 10 back-to-back f32x4 ----
        f32x4 r[CHUNK + 2];
        #pragma unroll
        for (int k = 0; k < CHUNK + 2; ++k) {
            const int y = base - 1 + k;
            f32x4 v = {0.f, 0.f, 0.f, 0.f};
            if (y >= 0 && y < HH)
                v = *reinterpret_cast<const f32x4*>(in + y * WW + col);
            r[k] = v;
        }

        // ---- Halo exchange (VALU/DS pipe, off the HBM path) ----
        // Lanes 31/32 straddle two ty-bands, but those are exactly the
        // x=-1 / x=128 zero-pad cases, masked by tx below.
        float lw[CHUNK + 2], rx[CHUNK + 2];
        #pragma unroll
        for (int k = 0; k < CHUNK + 2; ++k) {
            const float l = __shfl_up(r[k].w, 1);
            const float rr = __shfl_down(r[k].x, 1);
            lw[k] = (tx == 0)  ? 0.f : l;
            rx[k] = (tx == 31) ? 0.f : rr;
        }

        // ---- Compute + store burst ----
        #pragma unroll
        for (int i = 0; i < CHUNK; ++i) {
            // window rows: t = i, m = i+1, b = i+2 (input rows base+i-1..base+i+1)
            const f32x4 vt = r[i],     vm = r[i + 1],     vb = r[i + 2];
            const float t0 = lw[i],     m0 = lw[i + 1],    b0 = lw[i + 2];
            const float t5 = rx[i],     m5 = rx[i + 1],    b5 = rx[i + 2];

            // SOBEL_X = [[1,0,-1],[2,0,-2],[1,0,-1]] (cross-correlation, no flip)
            f32x4 gx;
            gx.x = (t0   - vt.y) + 2.f * (m0   - vm.y) + (b0   - vb.y);
            gx.y = (vt.x - vt.z) + 2.f * (vm.x - vm.z) + (vb.x - vb.z);
            gx.z = (vt.y - vt.w) + 2.f * (vm.y - vm.w) + (vb.y - vb.w);
            gx.w = (vt.z - t5  ) + 2.f * (vm.z - m5  ) + (vb.z - b5  );

            // SOBEL_Y = [[1,2,1],[0,0,0],[-1,-2,-1]]
            f32x4 gy;
            gy.x = (t0   + 2.f * vt.x + vt.y) - (b0   + 2.f * vb.x + vb.y);
            gy.y = (vt.x + 2.f * vt.y + vt.z) - (vb.x + 2.f * vb.y + vb.z);
            gy.z = (vt.y + 2.f * vt.z + vt.w) - (vb.y + 2.f * vb.z + vb.w);
            gy.w = (vt.z + 2.f * vt.w + t5  ) - (vb.z + 2.f * vb.w + b5  );

            // Outputs are write-once, never re-read: nt stores avoid L2/L3
            // write-allocate so input lines stay cache-resident.
            const int y = base + i;
            __builtin_nontemporal_store(gx, reinterpret_cast<f32x4*>(out_sx + (size_t)y * WW + col));
            __builtin_nontemporal_store(gy, reinterpret_cast<f32x4*>(out_sy + (size_t)y * WW + col));
        }
    }
}

extern "C" void kernel_launch(void* const* d_in, const int* in_sizes, int n_in,
                              void* d_out, int out_size, void* d_ws, size_t ws_size,
                              hipStream_t stream) {
    const float* f1 = (const float*)d_in[0];
    const float* f2 = (const float*)d_in[1];
    float* out = (float*)d_out;

    dim3 grid(PLANES * 2);   // one block per (plane, input) = 2048 blocks
    dim3 block(32, 8);       // 256 threads: 32 col-strips x 8 row-bands
    sobel_fused_kernel<<<grid, block, 0, stream>>>(f1, f2, out);
}